// Round 7
// baseline (240.952 us; speedup 1.0000x reference)
//
#include <hip/hip_runtime.h>
#include <hip/hip_bf16.h>

#define BATCH 16
#define SEQL  4096
#define NH    16
#define HD    64
#define HID   1024
#define KV_ELEMS (BATCH * NH * SEQL * HD)  // 67108864
#define C2 0.1803368801f         // 0.125 * log2(e)

#define NBLK  2048               // sweep blocks (8/CU x 256 CU, all resident)
#define NTILE 65536              // 4KB tiles covering K (= V): 16 rows each
#define TPB   (NTILE / NBLK)     // 32 tiles per block

#define NCHUNK 8                 // fallback path only
#define CHUNK  512
#define PSTRIDE 68

typedef float f4 __attribute__((ext_vector_type(4)));

// ---------------------------------------------------------------------------
// Kernel 1: single-pass batched GEMV.  out[w][b][o] = x[b][:] . W[o][:] + bias
// ---------------------------------------------------------------------------
__global__ __launch_bounds__(256) void gemv3(
    const float* __restrict__ x,
    const float* __restrict__ W0, const float* __restrict__ W1,
    const float* __restrict__ W2,
    const float* __restrict__ b0, const float* __restrict__ b1,
    const float* __restrict__ b2,
    float* __restrict__ out)
{
    __shared__ float xs[BATCH * HID];
    const int t = threadIdx.x;
    {
        const f4* src = (const f4*)x;
        f4* dst = (f4*)xs;
        #pragma unroll
        for (int i = 0; i < (BATCH * HID / 4) / 256; ++i)
            dst[t + i * 256] = src[t + i * 256];
    }
    __syncthreads();

    const int which = blockIdx.x >> 8;
    const int ob    = (blockIdx.x & 255) << 2;
    const float* W    = (which == 0) ? W0 : ((which == 1) ? W1 : W2);
    const float* bias = (which == 0) ? b0 : ((which == 1) ? b1 : b2);
    const int col = t >> 6, lane = t & 63;
    const int o = ob + col;
    const float* wrow = W + (size_t)o * HID;

    float acc[BATCH];
    #pragma unroll
    for (int b = 0; b < BATCH; ++b) acc[b] = 0.f;

    #pragma unroll
    for (int i = 0; i < 4; ++i) {
        const int k = (lane << 2) + (i << 8);
        const f4 w4 = *(const f4*)&wrow[k];
        #pragma unroll
        for (int b = 0; b < BATCH; ++b) {
            const f4 h4 = *(const f4*)&xs[b * HID + k];
            acc[b] += w4.x * h4.x + w4.y * h4.y + w4.z * h4.z + w4.w * h4.w;
        }
    }

    #pragma unroll
    for (int b = 0; b < BATCH; ++b) {
        #pragma unroll
        for (int sh = 1; sh < 64; sh <<= 1)
            acc[b] += __shfl_xor(acc[b], sh);
    }
    if (lane == 0) {
        const float bb = bias[o];
        #pragma unroll
        for (int b = 0; b < BATCH; ++b)
            out[which * (BATCH * HID) + b * HID + o] = acc[b] + bb;
    }
}

// ---------------------------------------------------------------------------
// Kernel 2: COMPACT-WINDOW sweep. K/V as 65536 flat 4KB tiles (16 rows).
//   Block blk handles tiles tau*2048+blk -> all 2048 resident blocks access
//   one contiguous 8MB moving window per buffer (copy-like DRAM row locality).
//   Per tile: copy K+V (stale), score p per row, cross-group reduce, flush
//   per-tile partial {L, A[64]}. Row `pos` corrected exactly in merge2.
//   qkv row for tile's bh: q = qkv[bh*64 + d] (b*HID + h*HD + d == bh*64+d).
// ---------------------------------------------------------------------------
__global__ __launch_bounds__(256, 8) void attn_sweep(
    const float* __restrict__ qkv,
    const float* __restrict__ past_k,
    const float* __restrict__ past_v,
    const float* __restrict__ mask,    // [16][4096]
    float* __restrict__ kout,
    float* __restrict__ vout,
    float* __restrict__ Aws,           // [NTILE][64]  (256B-aligned records)
    float* __restrict__ Lws)           // [NTILE]
{
    const int blk = blockIdx.x;        // 0..2047
    const int t   = threadIdx.x;       // 0..255
    const int g   = t >> 4;            // group 0..15 (one row per group)
    const int j   = t & 15;            // lane in group (4 floats of D=64)
    const int w   = t >> 6;            // wave 0..3

    __shared__ float sw[4][64];
    __shared__ float slw[4];

    // --- prefetch tile 0 ---
    int tile = blk;
    size_t off = (size_t)tile * 1024 + (t << 2);
    f4 k0 = __builtin_nontemporal_load((const f4*)(past_k + off));
    f4 v0 = __builtin_nontemporal_load((const f4*)(past_v + off));
    f4 q0 = *(const f4*)&qkv[(tile >> 8) * HD + (j << 2)];
    float am0 = mask[((tile >> 12) << 12) + ((tile & 255) << 4) + g];

    #pragma unroll 1
    for (int tau = 0; tau < TPB; ++tau) {
        const size_t coff = off;
        const int ctile = tile;
        const f4 kc = k0, vc = v0, qc = q0;
        const float amc = am0;

        if (tau < TPB - 1) {           // issue next tile's loads early
            tile += NBLK;
            off = (size_t)tile * 1024 + (t << 2);
            k0 = __builtin_nontemporal_load((const f4*)(past_k + off));
            v0 = __builtin_nontemporal_load((const f4*)(past_v + off));
            q0 = *(const f4*)&qkv[(tile >> 8) * HD + (j << 2)];
            am0 = mask[((tile >> 12) << 12) + ((tile & 255) << 4) + g];
        }

        // copy-out (stale; pos fixed later)
        __builtin_nontemporal_store(kc, (f4*)(kout + coff));
        __builtin_nontemporal_store(vc, (f4*)(vout + coff));

        // score for this group's row
        float d = kc.x * qc.x + kc.y * qc.y + kc.z * qc.z + kc.w * qc.w;
        d += __shfl_xor(d, 1);
        d += __shfl_xor(d, 2);
        d += __shfl_xor(d, 4);
        d += __shfl_xor(d, 8);
        float pe = exp2f(d * C2);
        const float p = (amc > 0.f) ? pe : 0.f;

        // per-lane contribution, reduce across the wave's 4 groups
        f4 c4 = { p * vc.x, p * vc.y, p * vc.z, p * vc.w };
        float pw = p;
        c4.x += __shfl_xor(c4.x, 16);  c4.x += __shfl_xor(c4.x, 32);
        c4.y += __shfl_xor(c4.y, 16);  c4.y += __shfl_xor(c4.y, 32);
        c4.z += __shfl_xor(c4.z, 16);  c4.z += __shfl_xor(c4.z, 32);
        c4.w += __shfl_xor(c4.w, 16);  c4.w += __shfl_xor(c4.w, 32);
        pw  += __shfl_xor(pw, 16);     pw  += __shfl_xor(pw, 32);

        if (((t >> 4) & 3) == 0) *(f4*)&sw[w][j << 2] = c4;
        if ((t & 63) == 0) slw[w] = pw;
        __syncthreads();

        if (t < 64) {
            const float A = sw[0][t] + sw[1][t] + sw[2][t] + sw[3][t];
            Aws[((size_t)ctile << 6) + t] = A;
            if (t == 0)
                Lws[ctile] = slw[0] + slw[1] + slw[2] + slw[3];
        }
        __syncthreads();
    }
}

// ---------------------------------------------------------------------------
// Kernel 3: per (b,h): sum 256 tile partials, fix row `pos` exactly
//           (overwrite cache row, swap stale->new score term), -> ctx.
// ---------------------------------------------------------------------------
__global__ __launch_bounds__(64) void merge2(
    const float* __restrict__ qkv,
    const float* __restrict__ past_k,
    const float* __restrict__ past_v,
    const float* __restrict__ mask,
    const int*   __restrict__ cpos,
    float* __restrict__ kout,
    float* __restrict__ vout,
    const float* __restrict__ Aws,
    const float* __restrict__ Lws,
    float* __restrict__ ctx)
{
    const int bh = blockIdx.x;
    const int b = bh >> 4;
    const int t = threadIdx.x;          // 0..63 (= head dim)
    const int pos = cpos[b];

    float L = 0.f, A = 0.f;
    const float* Ab = Aws + ((size_t)bh << 14);   // 256 tiles * 64
    const float* Lb = Lws + bh * 256;
    #pragma unroll 4
    for (int i = 0; i < 256; ++i) {
        A += Ab[(i << 6) + t];
        L += Lb[i];
    }

    const size_t rowoff = (size_t)bh * (SEQL * HD) + (size_t)pos * HD + t;
    const int qo = bh * HD + t;
    const float qd  = qkv[qo];
    const float knd = qkv[BATCH * HID + qo];
    const float vnd = qkv[2 * BATCH * HID + qo];
    const float ksd = past_k[rowoff];
    const float vsd = past_v[rowoff];

    kout[rowoff] = knd;
    vout[rowoff] = vnd;

    float dst = qd * ksd, dnw = qd * knd;
    #pragma unroll
    for (int sh = 1; sh < 64; sh <<= 1) {
        dst += __shfl_xor(dst, sh);
        dnw += __shfl_xor(dnw, sh);
    }
    const float am = mask[b * SEQL + pos];
    float ps = 0.f, pn = 0.f;
    if (am > 0.f) { ps = exp2f(dst * C2); pn = exp2f(dnw * C2); }

    L += pn - ps;
    A += pn * vnd - ps * vsd;
    ctx[bh * HD + t] = A / L;
}

// ---------------------------------------------------------------------------
// Fallback (R4 fused) — used only if ws can't hold the tile partials.
// ---------------------------------------------------------------------------
__global__ __launch_bounds__(256, 6) void attn_fused(
    const float* __restrict__ qkv,
    const float* __restrict__ past_k,
    const float* __restrict__ past_v,
    const float* __restrict__ mask,
    float* __restrict__ kout,
    float* __restrict__ vout,
    float* __restrict__ part)
{
    const int bh = blockIdx.x, c = blockIdx.y;
    const int b = bh >> 4, h = bh & 15;
    const int t = threadIdx.x;
    const int g = t >> 4, j = t & 15;

    const f4 q4 = *(const f4*)&qkv[b * HID + h * HD + (j << 2)];
    const size_t base = (size_t)bh * (SEQL * HD);
    const float* __restrict__ pkb = past_k + base;
    const float* __restrict__ pvb = past_v + base;
    float* __restrict__ kob = kout + base;
    float* __restrict__ vob = vout + base;
    const float* __restrict__ mrow = mask + b * SEQL;

    float l = 0.f;
    f4 a4 = {0.f, 0.f, 0.f, 0.f};

    #pragma unroll 1
    for (int s = 0; s < CHUNK / 128; ++s) {
        const int r0 = c * CHUNK + s * 128 + g;
        const int o0 = r0 * HD + (j << 2);

        f4 kx[8];
        float am[8];
        #pragma unroll
        for (int u = 0; u < 8; ++u)
            kx[u] = __builtin_nontemporal_load((const f4*)(pkb + o0 + u * (16 * HD)));
        #pragma unroll
        for (int u = 0; u < 8; ++u)
            am[u] = mrow[r0 + u * 16];
        #pragma unroll
        for (int u = 0; u < 8; ++u)
            __builtin_nontemporal_store(kx[u], (f4*)(kob + o0 + u * (16 * HD)));

        float p[8];
        #pragma unroll
        for (int u = 0; u < 8; ++u) {
            float d = kx[u].x * q4.x + kx[u].y * q4.y
                    + kx[u].z * q4.z + kx[u].w * q4.w;
            d += __shfl_xor(d, 1);
            d += __shfl_xor(d, 2);
            d += __shfl_xor(d, 4);
            d += __shfl_xor(d, 8);
            float pe = exp2f(d * C2);
            p[u] = (am[u] > 0.f) ? pe : 0.f;
            l += p[u];
        }

        f4 vx[8];
        #pragma unroll
        for (int u = 0; u < 8; ++u)
            vx[u] = __builtin_nontemporal_load((const f4*)(pvb + o0 + u * (16 * HD)));
        #pragma unroll
        for (int u = 0; u < 8; ++u)
            __builtin_nontemporal_store(vx[u], (f4*)(vob + o0 + u * (16 * HD)));
        #pragma unroll
        for (int u = 0; u < 8; ++u) {
            a4.x += p[u] * vx[u].x;
            a4.y += p[u] * vx[u].y;
            a4.z += p[u] * vx[u].z;
            a4.w += p[u] * vx[u].w;
        }
    }

    __shared__ float sl_[16];
    __shared__ float sa[16][64];
    if (j == 0) sl_[g] = l;
    *(f4*)&sa[g][(j << 2)] = a4;
    __syncthreads();

    float* pr = part + ((size_t)bh * NCHUNK + c) * PSTRIDE;
    if (t < 64) {
        float A = 0.f;
        #pragma unroll
        for (int gg = 0; gg < 16; ++gg) A += sa[gg][t];
        pr[1 + t] = A;
    } else if (t == 64) {
        float L = 0.f;
        #pragma unroll
        for (int gg = 0; gg < 16; ++gg) L += sl_[gg];
        pr[0] = L;
    }
}

__global__ __launch_bounds__(64) void merge_fix(
    const float* __restrict__ qkv,
    const float* __restrict__ past_k,
    const float* __restrict__ past_v,
    const float* __restrict__ mask,
    const int*   __restrict__ cpos,
    float* __restrict__ kout,
    float* __restrict__ vout,
    const float* __restrict__ part,
    float* __restrict__ ctx)
{
    const int bh = blockIdx.x;
    const int b = bh >> 4;
    const int t = threadIdx.x;
    const int pos = cpos[b];

    const size_t rowoff = (size_t)bh * (SEQL * HD) + (size_t)pos * HD + t;
    const int qo = bh * HD + t;
    const float qd  = qkv[qo];
    const float knd = qkv[BATCH * HID + qo];
    const float vnd = qkv[2 * BATCH * HID + qo];
    const float ksd = past_k[rowoff];
    const float vsd = past_v[rowoff];

    kout[rowoff] = knd;
    vout[rowoff] = vnd;

    float dst = qd * ksd, dnw = qd * knd;
    #pragma unroll
    for (int sh = 1; sh < 64; sh <<= 1) {
        dst += __shfl_xor(dst, sh);
        dnw += __shfl_xor(dnw, sh);
    }
    const float am = mask[b * SEQL + pos];
    float ps = 0.f, pn = 0.f;
    if (am > 0.f) { ps = exp2f(dst * C2); pn = exp2f(dnw * C2); }

    const int cc0 = pos / CHUNK;
    float L = 0.f, A = 0.f;
    #pragma unroll
    for (int cc = 0; cc < NCHUNK; ++cc) {
        const float* pr = part + ((size_t)bh * NCHUNK + cc) * PSTRIDE;
        float Lc = pr[0];
        float Ac = pr[1 + t];
        if (cc == cc0) { Lc += pn - ps; Ac += pn * vnd - ps * vsd; }
        L += Lc;
        A += Ac;
    }
    ctx[bh * HD + t] = A / L;
}

extern "C" void kernel_launch(void* const* d_in, const int* in_sizes, int n_in,
                              void* d_out, int out_size, void* d_ws, size_t ws_size,
                              hipStream_t stream) {
    const float* hs   = (const float*)d_in[0];
    const float* pk   = (const float*)d_in[1];
    const float* pv   = (const float*)d_in[2];
    const float* mask = (const float*)d_in[3];
    const int*   cpos = (const int*)d_in[4];
    const float* Wq   = (const float*)d_in[5];
    const float* bq   = (const float*)d_in[6];
    const float* Wk   = (const float*)d_in[7];
    const float* bk   = (const float*)d_in[8];
    const float* Wv   = (const float*)d_in[9];
    const float* bv   = (const float*)d_in[10];
    const float* Wo   = (const float*)d_in[11];
    const float* bo   = (const float*)d_in[12];

    float* out_attn = (float*)d_out;                 // 16384
    float* kout = out_attn + BATCH * HID;
    float* vout = kout + KV_ELEMS;

    float* ws    = (float*)d_ws;
    float* qkv   = ws;                  // 49152
    float* ctx   = ws + 49152;          // 16384 -> 65536
    float* apart = ws + 65536;          // fallback partials -> 204800
    float* Lws   = ws + 65536;          // sweep: L per tile (65536) -> 131072
    float* Aws   = ws + 131072;         // sweep: A per tile (NTILE*64)

    const size_t need_sweep = (size_t)(131072 + (size_t)NTILE * 64) * sizeof(float);
    const bool sweep_ok = ws_size >= need_sweep;

    gemv3<<<dim3(768), 256, 0, stream>>>(hs, Wq, Wk, Wv, bq, bk, bv, qkv);

    if (sweep_ok) {
        attn_sweep<<<dim3(NBLK), 256, 0, stream>>>(qkv, pk, pv, mask,
                                                   kout, vout, Aws, Lws);
        merge2<<<dim3(256), 64, 0, stream>>>(qkv, pk, pv, mask, cpos,
                                             kout, vout, Aws, Lws, ctx);
    } else {
        attn_fused<<<dim3(256, NCHUNK), 256, 0, stream>>>(qkv, pk, pv, mask,
                                                          kout, vout, apart);
        merge_fix<<<dim3(256), 64, 0, stream>>>(qkv, pk, pv, mask, cpos,
                                                kout, vout, apart, ctx);
    }

    gemv3<<<dim3(256), 256, 0, stream>>>(ctx, Wo, Wo, Wo, bo, bo, bo, out_attn);
}

// Round 8
// 223.199 us; speedup vs baseline: 1.0795x; 1.0795x over previous
//
#include <hip/hip_runtime.h>
#include <hip/hip_bf16.h>

#define BATCH 16
#define SEQL  4096
#define NH    16
#define HD    64
#define HID   1024
#define KV_ELEMS (BATCH * NH * SEQL * HD)  // 67108864
#define C2 0.1803368801f         // 0.125 * log2(e)

#define NBLK  2048               // sweep blocks
#define NWV   (NBLK * 4)         // 8192 waves
#define NTILE 65536              // 4KB wave-tiles (16 rows each)
#define TPW   (NTILE / NWV)      // 8 tiles per wave

#define NCHUNK 8                 // fallback path only
#define CHUNK  512
#define PSTRIDE 68

typedef float f4 __attribute__((ext_vector_type(4)));

#define NT_LOAD(p)    __builtin_nontemporal_load((const f4*)(p))
#define NT_STORE(v,p) __builtin_nontemporal_store((v), (f4*)(p))

// ---------------------------------------------------------------------------
// Kernel 1: single-pass batched GEMV.  out[w][b][o] = x[b][:] . W[o][:] + bias
// ---------------------------------------------------------------------------
__global__ __launch_bounds__(256) void gemv3(
    const float* __restrict__ x,
    const float* __restrict__ W0, const float* __restrict__ W1,
    const float* __restrict__ W2,
    const float* __restrict__ b0, const float* __restrict__ b1,
    const float* __restrict__ b2,
    float* __restrict__ out)
{
    __shared__ float xs[BATCH * HID];
    const int t = threadIdx.x;
    {
        const f4* src = (const f4*)x;
        f4* dst = (f4*)xs;
        #pragma unroll
        for (int i = 0; i < (BATCH * HID / 4) / 256; ++i)
            dst[t + i * 256] = src[t + i * 256];
    }
    __syncthreads();

    const int which = blockIdx.x >> 8;
    const int ob    = (blockIdx.x & 255) << 2;
    const float* W    = (which == 0) ? W0 : ((which == 1) ? W1 : W2);
    const float* bias = (which == 0) ? b0 : ((which == 1) ? b1 : b2);
    const int col = t >> 6, lane = t & 63;
    const int o = ob + col;
    const float* wrow = W + (size_t)o * HID;

    float acc[BATCH];
    #pragma unroll
    for (int b = 0; b < BATCH; ++b) acc[b] = 0.f;

    #pragma unroll
    for (int i = 0; i < 4; ++i) {
        const int k = (lane << 2) + (i << 8);
        const f4 w4 = *(const f4*)&wrow[k];
        #pragma unroll
        for (int b = 0; b < BATCH; ++b) {
            const f4 h4 = *(const f4*)&xs[b * HID + k];
            acc[b] += w4.x * h4.x + w4.y * h4.y + w4.z * h4.z + w4.w * h4.w;
        }
    }

    #pragma unroll
    for (int b = 0; b < BATCH; ++b) {
        #pragma unroll
        for (int sh = 1; sh < 64; sh <<= 1)
            acc[b] += __shfl_xor(acc[b], sh);
    }
    if (lane == 0) {
        const float bb = bias[o];
        #pragma unroll
        for (int b = 0; b < BATCH; ++b)
            out[which * (BATCH * HID) + b * HID + o] = acc[b] + bb;
    }
}

// ---------------------------------------------------------------------------
// Kernel 2: BARRIER-FREE compact-window sweep.
//   65536 wave-tiles of 16 rows (4KB). Wave wv handles tiles wv + i*8192:
//   the whole GPU sweeps one ~32MB moving window per buffer (copy-like DRAM
//   locality). All reductions are intra-wave shfl -> no barriers, no LDS,
//   stores never drain. Register A/B double-buffer, all indices static.
//   Row `pos` streamed stale; corrected exactly in merge2.
// ---------------------------------------------------------------------------
#define PROCESS(KX, VX, TILE, OFF)                                         \
  {                                                                        \
    const int bh_ = (TILE) >> 8;                                           \
    const int b_  = (TILE) >> 12;                                          \
    const int sq_ = ((TILE) & 255) << 4;                                   \
    const f4 q_ = *(const f4*)&qkv[(bh_ << 6) + col4];                     \
    float l_ = 0.f;                                                        \
    f4 a_ = {0.f, 0.f, 0.f, 0.f};                                          \
    _Pragma("unroll")                                                      \
    for (int u = 0; u < 4; ++u) {                                          \
      NT_STORE(KX[u], kout + (OFF) + (u << 8) + (lane << 2));              \
      NT_STORE(VX[u], vout + (OFF) + (u << 8) + (lane << 2));              \
      const float am_ = mask[(b_ << 12) + sq_ + (u << 2) + grp];           \
      float d_ = KX[u].x * q_.x + KX[u].y * q_.y                           \
               + KX[u].z * q_.z + KX[u].w * q_.w;                          \
      d_ += __shfl_xor(d_, 1);                                             \
      d_ += __shfl_xor(d_, 2);                                             \
      d_ += __shfl_xor(d_, 4);                                             \
      d_ += __shfl_xor(d_, 8);                                             \
      float pe_ = exp2f(d_ * C2);                                          \
      const float p_ = (am_ > 0.f) ? pe_ : 0.f;                            \
      l_ += p_;                                                            \
      a_.x += p_ * VX[u].x;  a_.y += p_ * VX[u].y;                         \
      a_.z += p_ * VX[u].z;  a_.w += p_ * VX[u].w;                         \
    }                                                                      \
    a_.x += __shfl_xor(a_.x, 16);  a_.x += __shfl_xor(a_.x, 32);           \
    a_.y += __shfl_xor(a_.y, 16);  a_.y += __shfl_xor(a_.y, 32);           \
    a_.z += __shfl_xor(a_.z, 16);  a_.z += __shfl_xor(a_.z, 32);           \
    a_.w += __shfl_xor(a_.w, 16);  a_.w += __shfl_xor(a_.w, 32);           \
    l_   += __shfl_xor(l_, 16);    l_   += __shfl_xor(l_, 32);             \
    if (lane < 16)                                                         \
      *(f4*)&Aws[((size_t)(TILE) << 6) + col4] = a_;                       \
    else if (lane == 16)                                                   \
      Lws[TILE] = l_;                                                      \
  }

__global__ __launch_bounds__(256, 5) void attn_wsweep(
    const float* __restrict__ qkv,
    const float* __restrict__ past_k,
    const float* __restrict__ past_v,
    const float* __restrict__ mask,    // [16][4096]
    float* __restrict__ kout,
    float* __restrict__ vout,
    float* __restrict__ Aws,           // [NTILE][64]
    float* __restrict__ Lws)           // [NTILE]
{
    const int t    = threadIdx.x;
    const int lane = t & 63;
    const int wv   = (blockIdx.x << 2) + (t >> 6);   // 0..8191
    const int grp  = lane >> 4;                      // row strip 0..3
    const int col4 = (lane & 15) << 2;               // column*4

    f4 kA[4], vA[4], kB[4], vB[4];

    int tileA = wv;
    size_t oA = (size_t)tileA << 10;
    #pragma unroll
    for (int u = 0; u < 4; ++u) {
        kA[u] = NT_LOAD(past_k + oA + (u << 8) + (lane << 2));
        vA[u] = NT_LOAD(past_v + oA + (u << 8) + (lane << 2));
    }

    #pragma unroll
    for (int kk = 0; kk < TPW / 2; ++kk) {
        const int tileB = tileA + NWV;
        const size_t oB = (size_t)tileB << 10;
        #pragma unroll
        for (int u = 0; u < 4; ++u) {
            kB[u] = NT_LOAD(past_k + oB + (u << 8) + (lane << 2));
            vB[u] = NT_LOAD(past_v + oB + (u << 8) + (lane << 2));
        }

        PROCESS(kA, vA, tileA, oA);

        if (kk < TPW / 2 - 1) {
            tileA = tileB + NWV;
            oA = (size_t)tileA << 10;
            #pragma unroll
            for (int u = 0; u < 4; ++u) {
                kA[u] = NT_LOAD(past_k + oA + (u << 8) + (lane << 2));
                vA[u] = NT_LOAD(past_v + oA + (u << 8) + (lane << 2));
            }
        }

        PROCESS(kB, vB, tileB, oB);
    }
}

// ---------------------------------------------------------------------------
// Kernel 3: per (b,h): sum 256 tile partials, fix row `pos` exactly
//           (overwrite cache row, swap stale->new score term), -> ctx.
// ---------------------------------------------------------------------------
__global__ __launch_bounds__(64) void merge2(
    const float* __restrict__ qkv,
    const float* __restrict__ past_k,
    const float* __restrict__ past_v,
    const float* __restrict__ mask,
    const int*   __restrict__ cpos,
    float* __restrict__ kout,
    float* __restrict__ vout,
    const float* __restrict__ Aws,
    const float* __restrict__ Lws,
    float* __restrict__ ctx)
{
    const int bh = blockIdx.x;
    const int b = bh >> 4;
    const int t = threadIdx.x;          // 0..63 (= head dim)
    const int pos = cpos[b];

    float L = 0.f, A = 0.f;
    const float* Ab = Aws + ((size_t)bh << 14);   // 256 tiles * 64
    const float* Lb = Lws + bh * 256;
    #pragma unroll 4
    for (int i = 0; i < 256; ++i) {
        A += Ab[(i << 6) + t];
        L += Lb[i];
    }

    const size_t rowoff = (size_t)bh * (SEQL * HD) + (size_t)pos * HD + t;
    const int qo = bh * HD + t;
    const float qd  = qkv[qo];
    const float knd = qkv[BATCH * HID + qo];
    const float vnd = qkv[2 * BATCH * HID + qo];
    const float ksd = past_k[rowoff];
    const float vsd = past_v[rowoff];

    kout[rowoff] = knd;
    vout[rowoff] = vnd;

    float dst = qd * ksd, dnw = qd * knd;
    #pragma unroll
    for (int sh = 1; sh < 64; sh <<= 1) {
        dst += __shfl_xor(dst, sh);
        dnw += __shfl_xor(dnw, sh);
    }
    const float am = mask[b * SEQL + pos];
    float ps = 0.f, pn = 0.f;
    if (am > 0.f) { ps = exp2f(dst * C2); pn = exp2f(dnw * C2); }

    L += pn - ps;
    A += pn * vnd - ps * vsd;
    ctx[bh * HD + t] = A / L;
}

// ---------------------------------------------------------------------------
// Fallback (R4 fused) — used only if ws can't hold the tile partials.
// ---------------------------------------------------------------------------
__global__ __launch_bounds__(256, 6) void attn_fused(
    const float* __restrict__ qkv,
    const float* __restrict__ past_k,
    const float* __restrict__ past_v,
    const float* __restrict__ mask,
    float* __restrict__ kout,
    float* __restrict__ vout,
    float* __restrict__ part)
{
    const int bh = blockIdx.x, c = blockIdx.y;
    const int b = bh >> 4, h = bh & 15;
    const int t = threadIdx.x;
    const int g = t >> 4, j = t & 15;

    const f4 q4 = *(const f4*)&qkv[b * HID + h * HD + (j << 2)];
    const size_t base = (size_t)bh * (SEQL * HD);
    const float* __restrict__ pkb = past_k + base;
    const float* __restrict__ pvb = past_v + base;
    float* __restrict__ kob = kout + base;
    float* __restrict__ vob = vout + base;
    const float* __restrict__ mrow = mask + b * SEQL;

    float l = 0.f;
    f4 a4 = {0.f, 0.f, 0.f, 0.f};

    #pragma unroll 1
    for (int s = 0; s < CHUNK / 128; ++s) {
        const int r0 = c * CHUNK + s * 128 + g;
        const int o0 = r0 * HD + (j << 2);

        f4 kx[8];
        float am[8];
        #pragma unroll
        for (int u = 0; u < 8; ++u)
            kx[u] = NT_LOAD(pkb + o0 + u * (16 * HD));
        #pragma unroll
        for (int u = 0; u < 8; ++u)
            am[u] = mrow[r0 + u * 16];
        #pragma unroll
        for (int u = 0; u < 8; ++u)
            NT_STORE(kx[u], kob + o0 + u * (16 * HD));

        float p[8];
        #pragma unroll
        for (int u = 0; u < 8; ++u) {
            float d = kx[u].x * q4.x + kx[u].y * q4.y
                    + kx[u].z * q4.z + kx[u].w * q4.w;
            d += __shfl_xor(d, 1);
            d += __shfl_xor(d, 2);
            d += __shfl_xor(d, 4);
            d += __shfl_xor(d, 8);
            float pe = exp2f(d * C2);
            p[u] = (am[u] > 0.f) ? pe : 0.f;
            l += p[u];
        }

        f4 vx[8];
        #pragma unroll
        for (int u = 0; u < 8; ++u)
            vx[u] = NT_LOAD(pvb + o0 + u * (16 * HD));
        #pragma unroll
        for (int u = 0; u < 8; ++u)
            NT_STORE(vx[u], vob + o0 + u * (16 * HD));
        #pragma unroll
        for (int u = 0; u < 8; ++u) {
            a4.x += p[u] * vx[u].x;
            a4.y += p[u] * vx[u].y;
            a4.z += p[u] * vx[u].z;
            a4.w += p[u] * vx[u].w;
        }
    }

    __shared__ float sl_[16];
    __shared__ float sa[16][64];
    if (j == 0) sl_[g] = l;
    *(f4*)&sa[g][(j << 2)] = a4;
    __syncthreads();

    float* pr = part + ((size_t)bh * NCHUNK + c) * PSTRIDE;
    if (t < 64) {
        float A = 0.f;
        #pragma unroll
        for (int gg = 0; gg < 16; ++gg) A += sa[gg][t];
        pr[1 + t] = A;
    } else if (t == 64) {
        float L = 0.f;
        #pragma unroll
        for (int gg = 0; gg < 16; ++gg) L += sl_[gg];
        pr[0] = L;
    }
}

__global__ __launch_bounds__(64) void merge_fix(
    const float* __restrict__ qkv,
    const float* __restrict__ past_k,
    const float* __restrict__ past_v,
    const float* __restrict__ mask,
    const int*   __restrict__ cpos,
    float* __restrict__ kout,
    float* __restrict__ vout,
    const float* __restrict__ part,
    float* __restrict__ ctx)
{
    const int bh = blockIdx.x;
    const int b = bh >> 4;
    const int t = threadIdx.x;
    const int pos = cpos[b];

    const size_t rowoff = (size_t)bh * (SEQL * HD) + (size_t)pos * HD + t;
    const int qo = bh * HD + t;
    const float qd  = qkv[qo];
    const float knd = qkv[BATCH * HID + qo];
    const float vnd = qkv[2 * BATCH * HID + qo];
    const float ksd = past_k[rowoff];
    const float vsd = past_v[rowoff];

    kout[rowoff] = knd;
    vout[rowoff] = vnd;

    float dst = qd * ksd, dnw = qd * knd;
    #pragma unroll
    for (int sh = 1; sh < 64; sh <<= 1) {
        dst += __shfl_xor(dst, sh);
        dnw += __shfl_xor(dnw, sh);
    }
    const float am = mask[b * SEQL + pos];
    float ps = 0.f, pn = 0.f;
    if (am > 0.f) { ps = exp2f(dst * C2); pn = exp2f(dnw * C2); }

    const int cc0 = pos / CHUNK;
    float L = 0.f, A = 0.f;
    #pragma unroll
    for (int cc = 0; cc < NCHUNK; ++cc) {
        const float* pr = part + ((size_t)bh * NCHUNK + cc) * PSTRIDE;
        float Lc = pr[0];
        float Ac = pr[1 + t];
        if (cc == cc0) { Lc += pn - ps; Ac += pn * vnd - ps * vsd; }
        L += Lc;
        A += Ac;
    }
    ctx[bh * HD + t] = A / L;
}

extern "C" void kernel_launch(void* const* d_in, const int* in_sizes, int n_in,
                              void* d_out, int out_size, void* d_ws, size_t ws_size,
                              hipStream_t stream) {
    const float* hs   = (const float*)d_in[0];
    const float* pk   = (const float*)d_in[1];
    const float* pv   = (const float*)d_in[2];
    const float* mask = (const float*)d_in[3];
    const int*   cpos = (const int*)d_in[4];
    const float* Wq   = (const float*)d_in[5];
    const float* bq   = (const float*)d_in[6];
    const float* Wk   = (const float*)d_in[7];
    const float* bk   = (const float*)d_in[8];
    const float* Wv   = (const float*)d_in[9];
    const float* bv   = (const float*)d_in[10];
    const float* Wo   = (const float*)d_in[11];
    const float* bo   = (const float*)d_in[12];

    float* out_attn = (float*)d_out;                 // 16384
    float* kout = out_attn + BATCH * HID;
    float* vout = kout + KV_ELEMS;

    float* ws    = (float*)d_ws;
    float* qkv   = ws;                  // 49152
    float* ctx   = ws + 49152;          // -> 65536
    float* apart = ws + 65536;          // fallback partials
    float* Lws   = ws + 65536;          // sweep: L per tile -> 131072
    float* Aws   = ws + 131072;         // sweep: A per tile (NTILE*64)

    const size_t need_sweep = (size_t)(131072 + (size_t)NTILE * 64) * sizeof(float);
    const bool sweep_ok = ws_size >= need_sweep;

    gemv3<<<dim3(768), 256, 0, stream>>>(hs, Wq, Wk, Wv, bq, bk, bv, qkv);

    if (sweep_ok) {
        attn_wsweep<<<dim3(NBLK), 256, 0, stream>>>(qkv, pk, pv, mask,
                                                    kout, vout, Aws, Lws);
        merge2<<<dim3(256), 64, 0, stream>>>(qkv, pk, pv, mask, cpos,
                                             kout, vout, Aws, Lws, ctx);
    } else {
        attn_fused<<<dim3(256, NCHUNK), 256, 0, stream>>>(qkv, pk, pv, mask,
                                                          kout, vout, apart);
        merge_fix<<<dim3(256), 64, 0, stream>>>(qkv, pk, pv, mask, cpos,
                                                kout, vout, apart, ctx);
    }

    gemv3<<<dim3(256), 256, 0, stream>>>(ctx, Wo, Wo, Wo, bo, bo, bo, out_attn);
}